// Round 5
// baseline (317.356 us; speedup 1.0000x reference)
//
#include <hip/hip_runtime.h>

#define Bb 2
#define Cc 64
#define Hh 48
#define Ww 48
#define Ll 48
#define HWc (Hh*Ww)          /* 2304 */
#define HWL (HWc*Ll)         /* 110592 */
#define GHh 24
#define SG (GHh*GHh*GHh)     /* 13824 */
#define NBLK (Bb*HWc)        /* 4608 */
#define CNT1f 110592.0f
#define CNT2f 9437184.0f     /* HW*C*C */

// half-pixel trilinear taps for 24 -> 48 (matches jax.image.resize 'trilinear')
__device__ __forceinline__ void interp1(int i, int& a, int& b, float& f){
  float src = i*0.5f - 0.25f;
  float fl = floorf(src);
  f = src - fl;
  int i0 = (int)fl;
  a = i0 < 0 ? 0 : i0;
  int i1 = i0 + 1;
  b = i1 > (GHh-1) ? (GHh-1) : i1;
}

// out[b,o,s] = sum_c W[o,c]*in[b,c,s] + bias[o]  — used only for theta_g (half-res)
__global__ __launch_bounds__(256) void conv_k(const float* __restrict__ in,
    const float* __restrict__ Wm, const float* __restrict__ bias,
    float* __restrict__ out, int S){
  __shared__ __align__(16) float Wl[64][68];   // Wl[c][o]
  __shared__ __align__(16) float xl[64][68];   // xl[c][s]
  int t = threadIdx.x;
  int ntile = S >> 6;
  int b  = blockIdx.x / ntile;
  int s0 = (blockIdx.x % ntile) << 6;
  for (int q = t; q < 4096; q += 256){
    int o = q >> 6, c = q & 63;
    Wl[c][o] = Wm[q];
  }
  const float* inb = in + (size_t)b*Cc*S + s0;
  for (int q = t; q < 1024; q += 256){
    int c = q >> 4, v = (q & 15) << 2;
    float4 val = *(const float4*)(inb + (size_t)c*S + v);
    *(float4*)&xl[c][v] = val;
  }
  __syncthreads();
  int o0 = (t & 15) << 2, s1 = (t >> 4) << 2;
  float a00=0,a01=0,a02=0,a03=0,a10=0,a11=0,a12=0,a13=0;
  float a20=0,a21=0,a22=0,a23=0,a30=0,a31=0,a32=0,a33=0;
  #pragma unroll 8
  for (int c = 0; c < 64; ++c){
    float4 wv = *(const float4*)&Wl[c][o0];
    float4 xv = *(const float4*)&xl[c][s1];
    a00 += wv.x*xv.x; a01 += wv.x*xv.y; a02 += wv.x*xv.z; a03 += wv.x*xv.w;
    a10 += wv.y*xv.x; a11 += wv.y*xv.y; a12 += wv.y*xv.z; a13 += wv.y*xv.w;
    a20 += wv.z*xv.x; a21 += wv.z*xv.y; a22 += wv.z*xv.z; a23 += wv.z*xv.w;
    a30 += wv.w*xv.x; a31 += wv.w*xv.y; a32 += wv.w*xv.z; a33 += wv.w*xv.w;
  }
  float* ob = out + (size_t)b*Cc*S + s0 + s1;
  float b0 = bias[o0+0], b1v = bias[o0+1], b2v = bias[o0+2], b3 = bias[o0+3];
  { float4 r = make_float4(a00+b0,a01+b0,a02+b0,a03+b0); *(float4*)(ob + (size_t)(o0+0)*S) = r; }
  { float4 r = make_float4(a10+b1v,a11+b1v,a12+b1v,a13+b1v); *(float4*)(ob + (size_t)(o0+1)*S) = r; }
  { float4 r = make_float4(a20+b2v,a21+b2v,a22+b2v,a23+b2v); *(float4*)(ob + (size_t)(o0+2)*S) = r; }
  { float4 r = make_float4(a30+b3,a31+b3,a32+b3,a33+b3); *(float4*)(ob + (size_t)(o0+3)*S) = r; }
}

// M[k][c] = bilinear(h,w) of half-res tgh (h-lerp then w-lerp).
// Shared by reduce_k and final_k so expanded tg values are bit-identical.
__device__ __forceinline__ void gather_m(const float* __restrict__ gb,
    float* __restrict__ M, int t, int ha, int hb, int wa, int wb,
    float fh, float fw){
  float omh = 1.f - fh, omw = 1.f - fw;
  for (int u = t; u < 384; u += 256){
    int c = u / 6, s4 = (u % 6) << 2;
    const float* gc = gb + (size_t)c*SG;
    float4 vaa = *(const float4*)(gc + ha*576 + wa*24 + s4);
    float4 vba = *(const float4*)(gc + hb*576 + wa*24 + s4);
    float4 vab = *(const float4*)(gc + ha*576 + wb*24 + s4);
    float4 vbb = *(const float4*)(gc + hb*576 + wb*24 + s4);
    M[(s4+0)*68 + c] = omw*(omh*vaa.x + fh*vba.x) + fw*(omh*vab.x + fh*vbb.x);
    M[(s4+1)*68 + c] = omw*(omh*vaa.y + fh*vba.y) + fw*(omh*vab.y + fh*vbb.y);
    M[(s4+2)*68 + c] = omw*(omh*vaa.z + fh*vba.z) + fw*(omh*vab.z + fh*vbb.z);
    M[(s4+3)*68 + c] = omw*(omh*vaa.w + fh*vba.w) + fw*(omh*vab.w + fh*vbb.w);
  }
}

// G-fold: G[k][c] = sum_l w(l,k)*txt[c][l] (txt stride 72) — transposed
// 48->24 interp weights.
__device__ __forceinline__ void g_fold(const float* __restrict__ txt,
    float* __restrict__ G, int t){
  int c = t >> 2, kb = (t & 3)*6;
  const float* T = &txt[c*72];
  #pragma unroll
  for (int i = 0; i < 6; ++i){
    int k = kb + i;
    float v;
    if (k == 0)       v = T[0] + 0.75f*T[1] + 0.25f*T[2];
    else if (k == 23) v = 0.25f*T[45] + 0.75f*T[46] + T[47];
    else              v = 0.25f*T[2*k-1] + 0.75f*T[2*k]
                        + 0.75f*T[2*k+1] + 0.25f*T[2*k+2];
    G[k*68 + c] = v;
  }
}

// per-site channel-mix (fused conv1): for thread-owned c0..c0+3, l0..l0+3:
// acc[i] (float4 over l) = sum_cc W1[c0+i][cc]*x[cc][l0..l0+3] + b1[c0+i].
// Serial cc chain -> bit-identical across reduce_k/final_k.
__device__ __forceinline__ void site_conv(const float* __restrict__ xs,
    const float* __restrict__ Wl, const float* __restrict__ b1,
    int c0, int l0, float4 acc[4]){
  acc[0] = make_float4(0.f,0.f,0.f,0.f);
  acc[1] = make_float4(0.f,0.f,0.f,0.f);
  acc[2] = make_float4(0.f,0.f,0.f,0.f);
  acc[3] = make_float4(0.f,0.f,0.f,0.f);
  #pragma unroll 8
  for (int cc = 0; cc < 64; ++cc){
    float4 wv = *(const float4*)&Wl[cc*72 + c0];   // W1[c0..c0+3][cc]
    float4 xv = *(const float4*)&xs[cc*52 + l0];
    acc[0].x += wv.x*xv.x; acc[0].y += wv.x*xv.y; acc[0].z += wv.x*xv.z; acc[0].w += wv.x*xv.w;
    acc[1].x += wv.y*xv.x; acc[1].y += wv.y*xv.y; acc[1].z += wv.y*xv.z; acc[1].w += wv.y*xv.w;
    acc[2].x += wv.z*xv.x; acc[2].y += wv.z*xv.y; acc[2].z += wv.z*xv.z; acc[2].w += wv.z*xv.w;
    acc[3].x += wv.w*xv.x; acc[3].y += wv.w*xv.y; acc[3].z += wv.w*xv.z; acc[3].w += wv.w*xv.w;
  }
  float b0 = b1[c0+0], bb1 = b1[c0+1], b2 = b1[c0+2], b3 = b1[c0+3];
  acc[0].x += b0;  acc[0].y += b0;  acc[0].z += b0;  acc[0].w += b0;
  acc[1].x += bb1; acc[1].y += bb1; acc[1].z += bb1; acc[1].w += bb1;
  acc[2].x += b2;  acc[2].y += b2;  acc[2].z += b2;  acc[2].w += b2;
  acc[3].x += b3;  acc[3].y += b3;  acc[3].z += b3;  acc[3].w += b3;
}

// one block per (b,h,w) site: fused conv1 + interp partials. No txw anywhere.
__global__ __launch_bounds__(256) void reduce_k(const float* __restrict__ x,
    const float* __restrict__ W1, const float* __restrict__ b1,
    const float* __restrict__ tgh, float* __restrict__ part_row,
    float* __restrict__ pm1, float* __restrict__ pm2, float* __restrict__ ps2){
  __shared__ __align__(16) float sh[11832];
  float* xs  = sh;            // [64][52]  raw x tile
  float* Wt  = sh + 3328;     // [64][72]  W1 (staged), then txt after conv
  float* M   = sh + 7936;     // [24][68]
  float* G   = sh + 9568;     // [24][68]
  float* red = sh + 11200;    // [512]
  float* CM  = sh + 11712;    // [24]
  float* SX  = sh + 11736;    // [48]
  float* sxg = sh + 11784;    // [48]
  int t = threadIdx.x;
  int bIdx = blockIdx.x;
  int b = bIdx / HWc, hw = bIdx % HWc;
  int h = hw / Ww, w = hw % Ww;
  int ha, hb; float fh; interp1(h, ha, hb, fh);
  int wa, wb; float fw; interp1(w, wa, wb, fw);
  const float* xb = x + ((size_t)b*Cc*HWc + hw)*Ll;
  #pragma unroll
  for (int k = 0; k < 3; ++k){
    int q = t + (k << 8);
    int c = q / 12, v = (q % 12) << 2;
    *(float4*)&xs[c*52+v] = *(const float4*)(xb + (size_t)c*HWL + v);
  }
  for (int q = t; q < 4096; q += 256){
    int o = q >> 6, c = q & 63;
    Wt[c*72 + o] = W1[q];
  }
  gather_m(tgh + (size_t)b*Cc*SG, M, t, ha, hb, wa, wb, fh, fw);
  __syncthreads();
  // fused conv1: txt in registers (192 threads, 4c x 4l each)
  int c0 = (t & 15) << 2, l0q = (t >> 4) << 2;
  float4 acc[4];
  if (t < 192) site_conv(xs, Wt, b1, c0, l0q, acc);
  if (t >= 192 && t < 216){
    int k = t - 192;
    float s = 0.f;
    #pragma unroll 8
    for (int c = 0; c < 64; ++c) s += M[k*68 + c];
    CM[k] = s;
  }
  __syncthreads();   // all W1/xs reads done
  if (t < 192){
    *(float4*)&Wt[(c0+0)*72 + l0q] = acc[0];
    *(float4*)&Wt[(c0+1)*72 + l0q] = acc[1];
    *(float4*)&Wt[(c0+2)*72 + l0q] = acc[2];
    *(float4*)&Wt[(c0+3)*72 + l0q] = acc[3];
  }
  __syncthreads();   // Wt now holds txt
  g_fold(Wt, G, t);
  if (t >= 192 && t < 240){
    int l = t - 192;
    float s = 0.f;
    #pragma unroll 8
    for (int c = 0; c < 64; ++c) s += Wt[c*72 + l];
    SX[l] = s;
  }
  __syncthreads();
  // elementwise product min (tg expanded on the fly, same lerp as final_k)
  int c = t & 63, lg = t >> 6;
  float pmin = 3.4e38f;
  const float* Trow = &Wt[c*72];
  #pragma unroll
  for (int li = 0; li < 12; ++li){
    int l = lg*12 + li;
    int la, lb; float fl; interp1(l, la, lb, fl);
    float tgv = (1.f-fl)*M[la*68 + c] + fl*M[lb*68 + c];
    pmin = fminf(pmin, Trow[l]*tgv);
  }
  if (t < 48){
    int la, lb; float fl; interp1(t, la, lb, fl);
    sxg[t] = SX[t] * ((1.f-fl)*CM[la] + fl*CM[lb]);
  }
  // At[i][j] = sum_k G[k][i]*M[k][j]; diag -> part_row (rowsum per channel)
  int i0 = (t & 15) << 2, j0 = (t >> 4) << 2;
  float a00=0,a01=0,a02=0,a03=0,a10=0,a11=0,a12=0,a13=0;
  float a20=0,a21=0,a22=0,a23=0,a30=0,a31=0,a32=0,a33=0;
  #pragma unroll 4
  for (int k = 0; k < 24; ++k){
    float4 gv = *(const float4*)&G[k*68 + i0];
    float4 mv = *(const float4*)&M[k*68 + j0];
    a00 += gv.x*mv.x; a01 += gv.x*mv.y; a02 += gv.x*mv.z; a03 += gv.x*mv.w;
    a10 += gv.y*mv.x; a11 += gv.y*mv.y; a12 += gv.y*mv.z; a13 += gv.y*mv.w;
    a20 += gv.z*mv.x; a21 += gv.z*mv.y; a22 += gv.z*mv.z; a23 += gv.z*mv.w;
    a30 += gv.w*mv.x; a31 += gv.w*mv.y; a32 += gv.w*mv.z; a33 += gv.w*mv.w;
  }
  float amin = fminf(fminf(fminf(a00,a01),fminf(a02,a03)),
               fminf(fminf(fminf(a10,a11),fminf(a12,a13)),
               fminf(fminf(fminf(a20,a21),fminf(a22,a23)),
                     fminf(fminf(a30,a31),fminf(a32,a33)))));
  if ((t & 15) == (t >> 4)){
    float* pr = part_row + (size_t)bIdx*64 + i0;
    pr[0] = a00; pr[1] = a11; pr[2] = a22; pr[3] = a33;
  }
  red[t] = pmin; red[256+t] = amin;
  __syncthreads();
  if (t < 128){
    red[t] = fminf(red[t], red[t+128]);
    red[256+t] = fminf(red[256+t], red[384+t]);
  }
  __syncthreads();
  if (t < 64){
    float v1 = fminf(red[t], red[t+64]);
    float v2 = fminf(red[256+t], red[320+t]);
    #pragma unroll
    for (int off = 32; off; off >>= 1){
      v1 = fminf(v1, __shfl_down(v1, off));
      v2 = fminf(v2, __shfl_down(v2, off));
    }
    if (t == 0){
      pm1[bIdx] = v1; pm2[bIdx] = v2;
      float tot = 0.f;
      #pragma unroll
      for (int l = 0; l < 48; ++l) tot += sxg[l];
      ps2[bIdx] = tot;
    }
  }
}

// parallel second-stage reduction: 130 blocks (unchanged)
__global__ __launch_bounds__(256) void reduce2_k(const float* __restrict__ part_row,
    const float* __restrict__ pm1, const float* __restrict__ pm2,
    const float* __restrict__ ps2, float* __restrict__ rowsum,
    float* __restrict__ gmin, float* __restrict__ s2v){
  __shared__ float red[512];
  int t = threadIdx.x, blk = blockIdx.x;
  if (blk < 128){
    int b = blk >> 6, c = blk & 63;
    const float* src = part_row + (size_t)b*HWc*64 + c;
    float s = 0.f;
    #pragma unroll
    for (int k = 0; k < 9; ++k){
      int i = t + (k << 8);
      s += src[(size_t)i*64];
    }
    red[t] = s; __syncthreads();
    for (int sgap = 128; sgap >= 64; sgap >>= 1){
      if (t < sgap) red[t] += red[t+sgap];
      __syncthreads();
    }
    if (t < 64){
      float v = red[t];
      #pragma unroll
      for (int off = 32; off; off >>= 1) v += __shfl_down(v, off);
      if (t == 0) rowsum[blk] = v;
    }
  } else if (blk == 128){
    float m1 = 3.4e38f, m2 = 3.4e38f;
    for (int i = t; i < NBLK; i += 256){ m1 = fminf(m1, pm1[i]); m2 = fminf(m2, pm2[i]); }
    red[t] = m1; red[256+t] = m2; __syncthreads();
    for (int s = 128; s >= 1; s >>= 1){
      if (t < s){ red[t] = fminf(red[t], red[t+s]); red[256+t] = fminf(red[256+t], red[256+t+s]); }
      __syncthreads();
    }
    if (t == 0){ gmin[0] = red[0]; gmin[1] = red[256]; }
  } else {
    float sa = 0.f, sb = 0.f;
    for (int i = t; i < HWc; i += 256){ sa += ps2[i]; sb += ps2[HWc + i]; }
    red[t] = sa; red[256+t] = sb; __syncthreads();
    for (int s = 128; s >= 1; s >>= 1){
      if (t < s){ red[t] += red[t+s]; red[256+t] += red[256+t+s]; }
      __syncthreads();
    }
    if (t == 0){ s2v[0] = red[0]; s2v[1] = red[256]; }
  }
}

// one block per (b,h,w): fused conv1 + p + d. txt recomputed (bit-identical
// to reduce_k); d via P[k][l]=sum_c G[k][c]*x[c][l], never forming At.
__global__ __launch_bounds__(256) void final_k(const float* __restrict__ x,
    const float* __restrict__ W1, const float* __restrict__ b1,
    const float* __restrict__ tgh, const float* __restrict__ gmin,
    const float* __restrict__ rowsum, const float* __restrict__ s2v,
    float* __restrict__ outp, float* __restrict__ outd){
  __shared__ __align__(16) float sh[11312];
  float* xs  = sh;            // [64][52]  raw x (alive throughout)
  float* Wt  = sh + 3328;     // [64][72]  W1 -> txt -> P[24][52]
  float* M   = sh + 7936;     // [24][68]
  float* G   = sh + 9568;     // [24][68]
  float* iv1 = sh + 11200;    // [64]
  float* Xs  = sh + 11264;    // [48]
  int t = threadIdx.x;
  int bIdx = blockIdx.x;
  int b = bIdx / HWc, hw = bIdx % HWc;
  int h = hw / Ww, w = hw % Ww;
  int ha, hb; float fh; interp1(h, ha, hb, fh);
  int wa, wb; float fw; interp1(w, wa, wb, fw);
  size_t sbase = ((size_t)b*Cc*HWc + hw)*Ll;
  const float* xb = x + sbase;
  float m1 = gmin[0], m2 = gmin[1];
  #pragma unroll
  for (int k = 0; k < 3; ++k){
    int q = t + (k << 8);
    int c = q / 12, v = (q % 12) << 2;
    *(float4*)&xs[c*52+v] = *(const float4*)(xb + (size_t)c*HWL + v);
  }
  for (int q = t; q < 4096; q += 256){
    int o = q >> 6, c = q & 63;
    Wt[c*72 + o] = W1[q];
  }
  gather_m(tgh + (size_t)b*Cc*SG, M, t, ha, hb, wa, wb, fh, fw);
  if (t < 64) iv1[t] = 1.f/(rowsum[b*64 + t] - m1*CNT1f);
  float invd2 = 1.f/(s2v[b] - m2*CNT2f);
  __syncthreads();
  int c0 = (t & 15) << 2, l0q = (t >> 4) << 2;
  float4 acc[4];
  if (t < 192) site_conv(xs, Wt, b1, c0, l0q, acc);
  if (t >= 192 && t < 240){
    int l = t - 192;
    float s = 0.f;
    #pragma unroll 8
    for (int c = 0; c < 64; ++c) s += xs[c*52 + l];
    Xs[l] = s;
  }
  __syncthreads();
  if (t < 192){
    *(float4*)&Wt[(c0+0)*72 + l0q] = acc[0];
    *(float4*)&Wt[(c0+1)*72 + l0q] = acc[1];
    *(float4*)&Wt[(c0+2)*72 + l0q] = acc[2];
    *(float4*)&Wt[(c0+3)*72 + l0q] = acc[3];
  }
  __syncthreads();   // Wt = txt
  g_fold(Wt, G, t);
  __syncthreads();
  // p = (tx*tg - m1)*iv1[c]*x, tg expanded from M (same lerp as reduce_k)
  #pragma unroll
  for (int k = 0; k < 3; ++k){
    int q = t + (k << 8);
    int c = q / 12, l4 = (q % 12) << 2;
    float4 a  = *(const float4*)&Wt[c*72+l4];
    float4 xv = *(const float4*)&xs[c*52+l4];
    float s = iv1[c];
    float4 r;
    {
      int la, lb; float fl; interp1(l4+0, la, lb, fl);
      float tgv = (1.f-fl)*M[la*68+c] + fl*M[lb*68+c];
      r.x = (a.x*tgv - m1)*s*xv.x;
    }
    {
      int la, lb; float fl; interp1(l4+1, la, lb, fl);
      float tgv = (1.f-fl)*M[la*68+c] + fl*M[lb*68+c];
      r.y = (a.y*tgv - m1)*s*xv.y;
    }
    {
      int la, lb; float fl; interp1(l4+2, la, lb, fl);
      float tgv = (1.f-fl)*M[la*68+c] + fl*M[lb*68+c];
      r.z = (a.z*tgv - m1)*s*xv.z;
    }
    {
      int la, lb; float fl; interp1(l4+3, la, lb, fl);
      float tgv = (1.f-fl)*M[la*68+c] + fl*M[lb*68+c];
      r.w = (a.w*tgv - m1)*s*xv.w;
    }
    *(float4*)(outp + sbase + (size_t)c*HWL + l4) = r;
  }
  __syncthreads();   // txt reads done; alias P over Wt
  float* P = Wt;     // [24][52]
  if (t < 192){
    int k0 = t >> 3, l0 = (t & 7)*6;
    float p0=0,p1=0,p2=0,p3=0,p4=0,p5=0;
    const float* Gr = &G[k0*68];
    #pragma unroll 8
    for (int i = 0; i < 64; ++i){
      float gv = Gr[i];
      const float* xr = &xs[i*52 + l0];
      p0 += gv*xr[0]; p1 += gv*xr[1]; p2 += gv*xr[2];
      p3 += gv*xr[3]; p4 += gv*xr[4]; p5 += gv*xr[5];
    }
    float* pr = &P[k0*52 + l0];
    pr[0]=p0; pr[1]=p1; pr[2]=p2; pr[3]=p3; pr[4]=p4; pr[5]=p5;
  }
  __syncthreads();
  // d[j][l] = invd2*(sum_k M[k][j]*P[k][l] - m2*Xs[l]); 256 thr: 4j x 3l each
  {
    int j0 = (t >> 4) << 2, l0 = (t & 15)*3;
    float d00=0,d01=0,d02=0,d10=0,d11=0,d12=0;
    float d20=0,d21=0,d22=0,d30=0,d31=0,d32=0;
    #pragma unroll 4
    for (int k = 0; k < 24; ++k){
      float4 mv = *(const float4*)&M[k*68 + j0];
      const float* pr = &P[k*52 + l0];
      float p0 = pr[0], p1 = pr[1], p2 = pr[2];
      d00 += mv.x*p0; d01 += mv.x*p1; d02 += mv.x*p2;
      d10 += mv.y*p0; d11 += mv.y*p1; d12 += mv.y*p2;
      d20 += mv.z*p0; d21 += mv.z*p1; d22 += mv.z*p2;
      d30 += mv.w*p0; d31 += mv.w*p1; d32 += mv.w*p2;
    }
    float x0 = m2*Xs[l0+0], x1 = m2*Xs[l0+1], x2 = m2*Xs[l0+2];
    float* o0 = outd + sbase + (size_t)(j0+0)*HWL + l0;
    float* o1 = outd + sbase + (size_t)(j0+1)*HWL + l0;
    float* o2 = outd + sbase + (size_t)(j0+2)*HWL + l0;
    float* o3 = outd + sbase + (size_t)(j0+3)*HWL + l0;
    o0[0]=(d00-x0)*invd2; o0[1]=(d01-x1)*invd2; o0[2]=(d02-x2)*invd2;
    o1[0]=(d10-x0)*invd2; o1[1]=(d11-x1)*invd2; o1[2]=(d12-x2)*invd2;
    o2[0]=(d20-x0)*invd2; o2[1]=(d21-x1)*invd2; o2[2]=(d22-x2)*invd2;
    o3[0]=(d30-x0)*invd2; o3[1]=(d31-x1)*invd2; o3[2]=(d32-x2)*invd2;
  }
}

extern "C" void kernel_launch(void* const* d_in, const int* in_sizes, int n_in,
                              void* d_out, int out_size, void* d_ws, size_t ws_size,
                              hipStream_t stream){
  (void)in_sizes; (void)n_in; (void)out_size; (void)ws_size;
  const float* x  = (const float*)d_in[0];
  const float* g  = (const float*)d_in[1];
  const float* W1 = (const float*)d_in[2];
  const float* b1 = (const float*)d_in[3];
  const float* W2 = (const float*)d_in[4];
  const float* b2 = (const float*)d_in[5];
  float* outp = (float*)d_out;
  float* outd = outp + (size_t)Bb*Cc*HWL;
  float* ws   = (float*)d_ws;
  float* tghw   = ws;                               // 1,769,472 floats
  float* part_row = tghw + (size_t)Bb*Cc*SG;        // NBLK*64
  float* pm1 = part_row + (size_t)NBLK*64;          // NBLK
  float* pm2 = pm1 + NBLK;                          // NBLK
  float* ps2 = pm2 + NBLK;                          // NBLK
  float* rowsum = ps2 + NBLK;                       // 128
  float* gmin = rowsum + 128;                       // 2
  float* s2v  = gmin + 2;                           // 2

  hipLaunchKernelGGL(conv_k, dim3(Bb*(SG/64)), dim3(256), 0, stream, g, W2, b2, tghw, SG);
  hipLaunchKernelGGL(reduce_k, dim3(NBLK), dim3(256), 0, stream, x, W1, b1, tghw,
                     part_row, pm1, pm2, ps2);
  hipLaunchKernelGGL(reduce2_k, dim3(130), dim3(256), 0, stream, part_row, pm1, pm2, ps2,
                     rowsum, gmin, s2v);
  hipLaunchKernelGGL(final_k, dim3(NBLK), dim3(256), 0, stream, x, W1, b1, tghw,
                     gmin, rowsum, s2v, outp, outd);
}

// Round 6
// 313.582 us; speedup vs baseline: 1.0120x; 1.0120x over previous
//
#include <hip/hip_runtime.h>

#define Bb 2
#define Cc 64
#define Hh 48
#define Ww 48
#define Ll 48
#define HWc (Hh*Ww)          /* 2304 */
#define HWL (HWc*Ll)         /* 110592 */
#define GHh 24
#define SG (GHh*GHh*GHh)     /* 13824 */
#define NBLK (Bb*HWc)        /* 4608 */
#define CNT1f 110592.0f
#define CNT2f 9437184.0f     /* HW*C*C */

// half-pixel trilinear taps for 24 -> 48 (matches jax.image.resize 'trilinear')
__device__ __forceinline__ void interp1(int i, int& a, int& b, float& f){
  float src = i*0.5f - 0.25f;
  float fl = floorf(src);
  f = src - fl;
  int i0 = (int)fl;
  a = i0 < 0 ? 0 : i0;
  int i1 = i0 + 1;
  b = i1 > (GHh-1) ? (GHh-1) : i1;
}

// out[b,o,s] = sum_c W[o,c]*in[b,c,s] + bias[o]
__global__ __launch_bounds__(256) void conv_k(const float* __restrict__ in,
    const float* __restrict__ Wm, const float* __restrict__ bias,
    float* __restrict__ out, int S){
  __shared__ __align__(16) float Wl[64][68];   // Wl[c][o]
  __shared__ __align__(16) float xl[64][68];   // xl[c][s]
  int t = threadIdx.x;
  int ntile = S >> 6;
  int b  = blockIdx.x / ntile;
  int s0 = (blockIdx.x % ntile) << 6;
  for (int q = t; q < 4096; q += 256){
    int o = q >> 6, c = q & 63;
    Wl[c][o] = Wm[q];
  }
  const float* inb = in + (size_t)b*Cc*S + s0;
  for (int q = t; q < 1024; q += 256){
    int c = q >> 4, v = (q & 15) << 2;
    float4 val = *(const float4*)(inb + (size_t)c*S + v);
    *(float4*)&xl[c][v] = val;
  }
  __syncthreads();
  int o0 = (t & 15) << 2, s1 = (t >> 4) << 2;
  float a00=0,a01=0,a02=0,a03=0,a10=0,a11=0,a12=0,a13=0;
  float a20=0,a21=0,a22=0,a23=0,a30=0,a31=0,a32=0,a33=0;
  #pragma unroll 8
  for (int c = 0; c < 64; ++c){
    float4 wv = *(const float4*)&Wl[c][o0];
    float4 xv = *(const float4*)&xl[c][s1];
    a00 += wv.x*xv.x; a01 += wv.x*xv.y; a02 += wv.x*xv.z; a03 += wv.x*xv.w;
    a10 += wv.y*xv.x; a11 += wv.y*xv.y; a12 += wv.y*xv.z; a13 += wv.y*xv.w;
    a20 += wv.z*xv.x; a21 += wv.z*xv.y; a22 += wv.z*xv.z; a23 += wv.z*xv.w;
    a30 += wv.w*xv.x; a31 += wv.w*xv.y; a32 += wv.w*xv.z; a33 += wv.w*xv.w;
  }
  float* ob = out + (size_t)b*Cc*S + s0 + s1;
  float b0 = bias[o0+0], b1v = bias[o0+1], b2v = bias[o0+2], b3 = bias[o0+3];
  { float4 r = make_float4(a00+b0,a01+b0,a02+b0,a03+b0); *(float4*)(ob + (size_t)(o0+0)*S) = r; }
  { float4 r = make_float4(a10+b1v,a11+b1v,a12+b1v,a13+b1v); *(float4*)(ob + (size_t)(o0+1)*S) = r; }
  { float4 r = make_float4(a20+b2v,a21+b2v,a22+b2v,a23+b2v); *(float4*)(ob + (size_t)(o0+2)*S) = r; }
  { float4 r = make_float4(a30+b3,a31+b3,a32+b3,a33+b3); *(float4*)(ob + (size_t)(o0+3)*S) = r; }
}

// G-fold: G[k][c] = sum_l w(l,k)*txt[c][l] (txt stride 52) — transposed
// 48->24 interp weights.
__device__ __forceinline__ void g_fold(const float* __restrict__ txt,
    float* __restrict__ G, int t){
  int c = t >> 2, kb = (t & 3)*6;
  const float* T = &txt[c*52];
  #pragma unroll
  for (int i = 0; i < 6; ++i){
    int k = kb + i;
    float v;
    if (k == 0)       v = T[0] + 0.75f*T[1] + 0.25f*T[2];
    else if (k == 23) v = 0.25f*T[45] + 0.75f*T[46] + T[47];
    else              v = 0.25f*T[2*k-1] + 0.75f*T[2*k]
                        + 0.75f*T[2*k+1] + 0.25f*T[2*k+2];
    G[k*68 + c] = v;
  }
}

// M[k][c] = bilinear(h,w) of half-res tgh (h-lerp then w-lerp).
__device__ __forceinline__ void gather_m(const float* __restrict__ gb,
    float* __restrict__ M, int t, int ha, int hb, int wa, int wb,
    float fh, float fw){
  float omh = 1.f - fh, omw = 1.f - fw;
  for (int u = t; u < 384; u += 256){
    int c = u / 6, s4 = (u % 6) << 2;
    const float* gc = gb + (size_t)c*SG;
    float4 vaa = *(const float4*)(gc + ha*576 + wa*24 + s4);
    float4 vba = *(const float4*)(gc + hb*576 + wa*24 + s4);
    float4 vab = *(const float4*)(gc + ha*576 + wb*24 + s4);
    float4 vbb = *(const float4*)(gc + hb*576 + wb*24 + s4);
    M[(s4+0)*68 + c] = omw*(omh*vaa.x + fh*vba.x) + fw*(omh*vab.x + fh*vbb.x);
    M[(s4+1)*68 + c] = omw*(omh*vaa.y + fh*vba.y) + fw*(omh*vab.y + fh*vbb.y);
    M[(s4+2)*68 + c] = omw*(omh*vaa.z + fh*vba.z) + fw*(omh*vab.z + fh*vbb.z);
    M[(s4+3)*68 + c] = omw*(omh*vaa.w + fh*vba.w) + fw*(omh*vab.w + fh*vbb.w);
  }
}

// one block per (b,h,w) site: per-site partials + msite store.
// rowsum per channel = diag(At) (no separate product-sum pass); pmin loop
// uses a c-rotated l-partition so txt reads spread over all 32 banks.
__global__ __launch_bounds__(256) void reduce_k(const float* __restrict__ tx,
    const float* __restrict__ tgh, float* __restrict__ msite,
    float* __restrict__ part_row, float* __restrict__ pm1,
    float* __restrict__ pm2, float* __restrict__ ps2){
  __shared__ __align__(16) float sh[7224];
  float* txt = sh;            // [64][52]
  float* M   = sh + 3328;     // [24][68]  k-major
  float* G   = sh + 4960;     // [24][68]  k-major
  float* red = sh + 6592;     // [512]
  float* CM  = sh + 7104;     // [24]
  float* SX  = sh + 7128;     // [48]
  float* sxg = sh + 7176;     // [48]
  int t = threadIdx.x;
  int bIdx = blockIdx.x;
  int b = bIdx / HWc, hw = bIdx % HWc;
  int h = hw / Ww, w = hw % Ww;
  int ha, hb; float fh; interp1(h, ha, hb, fh);
  int wa, wb; float fw; interp1(w, wa, wb, fw);
  const float* txb = tx + ((size_t)b*Cc*HWc + hw)*Ll;
  #pragma unroll
  for (int k = 0; k < 3; ++k){
    int q = t + (k << 8);
    int c = q / 12, v = (q % 12) << 2;
    *(float4*)&txt[c*52+v] = *(const float4*)(txb + (size_t)c*HWL + v);
  }
  gather_m(tgh + (size_t)b*Cc*SG, M, t, ha, hb, wa, wb, fh, fw);
  __syncthreads();
  g_fold(txt, G, t);
  if (t < 24){
    float s = 0.f;
    #pragma unroll 8
    for (int c = 0; c < 64; ++c) s += M[t*68 + c];
    CM[t] = s;
  }
  if (t >= 192 && t < 240){
    int l = t - 192;
    float s = 0.f;
    #pragma unroll 8
    for (int c = 0; c < 64; ++c) s += txt[c*52 + l];
    SX[l] = s;
  }
  __syncthreads();
  // elementwise product min; l-partition rotated by c to avoid the
  // stride-52 8-way bank conflict (address ~ 21c -> all 32 banks).
  int c = t & 63, lg = t >> 6;
  float pmin = 3.4e38f;
  const float* Trow = &txt[c*52];
  #pragma unroll
  for (int li = 0; li < 12; ++li){
    int l0r = lg*12 + li + c;                 // <= 110
    int l = l0r >= 96 ? l0r - 96 : (l0r >= 48 ? l0r - 48 : l0r);
    int la, lb; float fl; interp1(l, la, lb, fl);
    float tgv = (1.f-fl)*M[la*68 + c] + fl*M[lb*68 + c];
    pmin = fminf(pmin, Trow[l]*tgv);
  }
  if (t < 48){
    int la, lb; float fl; interp1(t, la, lb, fl);
    sxg[t] = SX[t] * ((1.f-fl)*CM[la] + fl*CM[lb]);
  }
  // store M site-major for final_k (contiguous, coalesced)
  float* msb = msite + (size_t)bIdx*1536;
  for (int u = t; u < 384; u += 256){
    int k = u >> 4, c4 = (u & 15) << 2;
    float4 mv;
    mv.x = M[k*68+c4+0]; mv.y = M[k*68+c4+1];
    mv.z = M[k*68+c4+2]; mv.w = M[k*68+c4+3];
    *(float4*)(msb + (u << 2)) = mv;
  }
  // At[i][j] = sum_k G[k][i]*M[k][j] — conflict-free; diag -> part_row
  int i0 = (t & 15) << 2, j0 = (t >> 4) << 2;
  float a00=0,a01=0,a02=0,a03=0,a10=0,a11=0,a12=0,a13=0;
  float a20=0,a21=0,a22=0,a23=0,a30=0,a31=0,a32=0,a33=0;
  #pragma unroll 4
  for (int k = 0; k < 24; ++k){
    float4 gv = *(const float4*)&G[k*68 + i0];
    float4 mv = *(const float4*)&M[k*68 + j0];
    a00 += gv.x*mv.x; a01 += gv.x*mv.y; a02 += gv.x*mv.z; a03 += gv.x*mv.w;
    a10 += gv.y*mv.x; a11 += gv.y*mv.y; a12 += gv.y*mv.z; a13 += gv.y*mv.w;
    a20 += gv.z*mv.x; a21 += gv.z*mv.y; a22 += gv.z*mv.z; a23 += gv.z*mv.w;
    a30 += gv.w*mv.x; a31 += gv.w*mv.y; a32 += gv.w*mv.z; a33 += gv.w*mv.w;
  }
  float amin = fminf(fminf(fminf(a00,a01),fminf(a02,a03)),
               fminf(fminf(fminf(a10,a11),fminf(a12,a13)),
               fminf(fminf(fminf(a20,a21),fminf(a22,a23)),
                     fminf(fminf(a30,a31),fminf(a32,a33)))));
  if ((t & 15) == (t >> 4)){
    // diagonal 4x4 block: a00,a11,a22,a33 = At[c][c] = rowsum partial
    float* pr = part_row + (size_t)bIdx*64 + i0;
    pr[0] = a00; pr[1] = a11; pr[2] = a22; pr[3] = a33;
  }
  red[t] = pmin; red[256+t] = amin;
  __syncthreads();
  if (t < 128){
    red[t] = fminf(red[t], red[t+128]);
    red[256+t] = fminf(red[256+t], red[384+t]);
  }
  __syncthreads();
  if (t < 64){
    float v1 = fminf(red[t], red[t+64]);
    float v2 = fminf(red[256+t], red[320+t]);
    #pragma unroll
    for (int off = 32; off; off >>= 1){
      v1 = fminf(v1, __shfl_down(v1, off));
      v2 = fminf(v2, __shfl_down(v2, off));
    }
    if (t == 0){
      pm1[bIdx] = v1; pm2[bIdx] = v2;
      float tot = 0.f;
      #pragma unroll
      for (int l = 0; l < 48; ++l) tot += sxg[l];
      ps2[bIdx] = tot;
    }
  }
}

// parallel second-stage reduction: 130 blocks (unchanged)
__global__ __launch_bounds__(256) void reduce2_k(const float* __restrict__ part_row,
    const float* __restrict__ pm1, const float* __restrict__ pm2,
    const float* __restrict__ ps2, float* __restrict__ rowsum,
    float* __restrict__ gmin, float* __restrict__ s2v){
  __shared__ float red[512];
  int t = threadIdx.x, blk = blockIdx.x;
  if (blk < 128){
    int b = blk >> 6, c = blk & 63;
    const float* src = part_row + (size_t)b*HWc*64 + c;
    float s = 0.f;
    #pragma unroll
    for (int k = 0; k < 9; ++k){
      int i = t + (k << 8);
      s += src[(size_t)i*64];
    }
    red[t] = s; __syncthreads();
    for (int sgap = 128; sgap >= 64; sgap >>= 1){
      if (t < sgap) red[t] += red[t+sgap];
      __syncthreads();
    }
    if (t < 64){
      float v = red[t];
      #pragma unroll
      for (int off = 32; off; off >>= 1) v += __shfl_down(v, off);
      if (t == 0) rowsum[blk] = v;
    }
  } else if (blk == 128){
    float m1 = 3.4e38f, m2 = 3.4e38f;
    for (int i = t; i < NBLK; i += 256){ m1 = fminf(m1, pm1[i]); m2 = fminf(m2, pm2[i]); }
    red[t] = m1; red[256+t] = m2; __syncthreads();
    for (int s = 128; s >= 1; s >>= 1){
      if (t < s){ red[t] = fminf(red[t], red[t+s]); red[256+t] = fminf(red[256+t], red[256+t+s]); }
      __syncthreads();
    }
    if (t == 0){ gmin[0] = red[0]; gmin[1] = red[256]; }
  } else {
    float sa = 0.f, sb = 0.f;
    for (int i = t; i < HWc; i += 256){ sa += ps2[i]; sb += ps2[HWc + i]; }
    red[t] = sa; red[256+t] = sb; __syncthreads();
    for (int s = 128; s >= 1; s >>= 1){
      if (t < s){ red[t] += red[t+s]; red[256+t] += red[256+t+s]; }
      __syncthreads();
    }
    if (t == 0){ s2v[0] = red[0]; s2v[1] = red[256]; }
  }
}

// one block per (b,h,w): p and d. At recomputed from G,M (K=24, conflict-free);
// tg expanded on the fly from M for p; At' aliases txt after p. (round-3 form)
__global__ __launch_bounds__(256) void final_k(const float* __restrict__ x,
    const float* __restrict__ tx, const float* __restrict__ msite,
    const float* __restrict__ gmin, const float* __restrict__ rowsum,
    const float* __restrict__ s2v, float* __restrict__ outp, float* __restrict__ outd){
  __shared__ __align__(16) float sh[9984];
  float* txt = sh;            // [64][52]  (At' aliases this after p)
  float* xs  = sh + 3328;     // [64][52]
  float* M   = sh + 6656;     // [24][68]
  float* G   = sh + 8288;     // [24][68]
  float* iv1 = sh + 9920;     // [64]
  int t = threadIdx.x;
  int bIdx = blockIdx.x;
  int b = bIdx / HWc, hw = bIdx % HWc;
  size_t sbase = ((size_t)b*Cc*HWc + hw)*Ll;
  const float* txb = tx + sbase;
  const float* xb  = x  + sbase;
  float m1 = gmin[0], m2 = gmin[1];
  #pragma unroll
  for (int k = 0; k < 3; ++k){
    int q = t + (k << 8);
    int c = q / 12, v = (q % 12) << 2;
    *(float4*)&txt[c*52+v] = *(const float4*)(txb + (size_t)c*HWL + v);
    *(float4*)&xs [c*52+v] = *(const float4*)(xb  + (size_t)c*HWL + v);
  }
  const float* msb = msite + (size_t)bIdx*1536;
  for (int u = t; u < 384; u += 256){
    float4 mv = *(const float4*)(msb + (u << 2));
    int k = u >> 4, c4 = (u & 15) << 2;
    *(float4*)&M[k*68 + c4] = mv;
  }
  if (t < 64) iv1[t] = 1.f/(rowsum[b*64 + t] - m1*CNT1f);
  float invd2 = 1.f/(s2v[b] - m2*CNT2f);
  __syncthreads();
  g_fold(txt, G, t);
  __syncthreads();
  // At[i][j] = sum_k G[k][i]*M[k][j]
  int i0 = (t & 15) << 2, j0 = (t >> 4) << 2;
  float a00=0,a01=0,a02=0,a03=0,a10=0,a11=0,a12=0,a13=0;
  float a20=0,a21=0,a22=0,a23=0,a30=0,a31=0,a32=0,a33=0;
  #pragma unroll 4
  for (int k = 0; k < 24; ++k){
    float4 gv = *(const float4*)&G[k*68 + i0];
    float4 mv = *(const float4*)&M[k*68 + j0];
    a00 += gv.x*mv.x; a01 += gv.x*mv.y; a02 += gv.x*mv.z; a03 += gv.x*mv.w;
    a10 += gv.y*mv.x; a11 += gv.y*mv.y; a12 += gv.y*mv.z; a13 += gv.y*mv.w;
    a20 += gv.z*mv.x; a21 += gv.z*mv.y; a22 += gv.z*mv.z; a23 += gv.z*mv.w;
    a30 += gv.w*mv.x; a31 += gv.w*mv.y; a32 += gv.w*mv.z; a33 += gv.w*mv.w;
  }
  // p = (tx*tg - m1)*iv1[c]*x, tg expanded from M rows (same lerp as reduce_k)
  #pragma unroll
  for (int k = 0; k < 3; ++k){
    int q = t + (k << 8);
    int c = q / 12, l4 = (q % 12) << 2;
    float4 a  = *(const float4*)&txt[c*52+l4];
    float4 xv = *(const float4*)&xs [c*52+l4];
    float s = iv1[c];
    float4 r;
    {
      int la, lb; float fl; interp1(l4+0, la, lb, fl);
      float tgv = (1.f-fl)*M[la*68+c] + fl*M[lb*68+c];
      r.x = (a.x*tgv - m1)*s*xv.x;
    }
    {
      int la, lb; float fl; interp1(l4+1, la, lb, fl);
      float tgv = (1.f-fl)*M[la*68+c] + fl*M[lb*68+c];
      r.y = (a.y*tgv - m1)*s*xv.y;
    }
    {
      int la, lb; float fl; interp1(l4+2, la, lb, fl);
      float tgv = (1.f-fl)*M[la*68+c] + fl*M[lb*68+c];
      r.z = (a.z*tgv - m1)*s*xv.z;
    }
    {
      int la, lb; float fl; interp1(l4+3, la, lb, fl);
      float tgv = (1.f-fl)*M[la*68+c] + fl*M[lb*68+c];
      r.w = (a.w*tgv - m1)*s*xv.w;
    }
    *(float4*)(outp + sbase + (size_t)c*HWL + l4) = r;
  }
  __syncthreads();   // txt reads (p) done; safe to overwrite with At'
  float* At = txt;   // At'[c][j] = (At[c][j]-m2)*invd2, stride 52
  { float4 r = make_float4((a00-m2)*invd2,(a01-m2)*invd2,(a02-m2)*invd2,(a03-m2)*invd2);
    *(float4*)&At[(i0+0)*52 + j0] = r; }
  { float4 r = make_float4((a10-m2)*invd2,(a11-m2)*invd2,(a12-m2)*invd2,(a13-m2)*invd2);
    *(float4*)&At[(i0+1)*52 + j0] = r; }
  { float4 r = make_float4((a20-m2)*invd2,(a21-m2)*invd2,(a22-m2)*invd2,(a23-m2)*invd2);
    *(float4*)&At[(i0+2)*52 + j0] = r; }
  { float4 r = make_float4((a30-m2)*invd2,(a31-m2)*invd2,(a32-m2)*invd2,(a33-m2)*invd2);
    *(float4*)&At[(i0+3)*52 + j0] = r; }
  __syncthreads();
  // d[j,l] = sum_c At'[c][j]*x[c][l]
  if (t < 192){
    int jj = (t & 15) << 2, l0 = (t >> 4) << 2;
    float d00=0,d01=0,d02=0,d03=0,d10=0,d11=0,d12=0,d13=0;
    float d20=0,d21=0,d22=0,d23=0,d30=0,d31=0,d32=0,d33=0;
    #pragma unroll 4
    for (int cc = 0; cc < 64; ++cc){
      float4 av = *(const float4*)&At[cc*52 + jj];
      float4 xv = *(const float4*)&xs[cc*52 + l0];
      d00 += av.x*xv.x; d01 += av.x*xv.y; d02 += av.x*xv.z; d03 += av.x*xv.w;
      d10 += av.y*xv.x; d11 += av.y*xv.y; d12 += av.y*xv.z; d13 += av.y*xv.w;
      d20 += av.z*xv.x; d21 += av.z*xv.y; d22 += av.z*xv.z; d23 += av.z*xv.w;
      d30 += av.w*xv.x; d31 += av.w*xv.y; d32 += av.w*xv.z; d33 += av.w*xv.w;
    }
    { float4 r = make_float4(d00,d01,d02,d03);
      *(float4*)(outd + sbase + (size_t)(jj+0)*HWL + l0) = r; }
    { float4 r = make_float4(d10,d11,d12,d13);
      *(float4*)(outd + sbase + (size_t)(jj+1)*HWL + l0) = r; }
    { float4 r = make_float4(d20,d21,d22,d23);
      *(float4*)(outd + sbase + (size_t)(jj+2)*HWL + l0) = r; }
    { float4 r = make_float4(d30,d31,d32,d33);
      *(float4*)(outd + sbase + (size_t)(jj+3)*HWL + l0) = r; }
  }
}

extern "C" void kernel_launch(void* const* d_in, const int* in_sizes, int n_in,
                              void* d_out, int out_size, void* d_ws, size_t ws_size,
                              hipStream_t stream){
  (void)in_sizes; (void)n_in; (void)out_size; (void)ws_size;
  const float* x  = (const float*)d_in[0];
  const float* g  = (const float*)d_in[1];
  const float* W1 = (const float*)d_in[2];
  const float* b1 = (const float*)d_in[3];
  const float* W2 = (const float*)d_in[4];
  const float* b2 = (const float*)d_in[5];
  float* outp = (float*)d_out;
  float* outd = outp + (size_t)Bb*Cc*HWL;
  float* ws   = (float*)d_ws;
  float* txw    = ws;                               // 14,155,776 floats
  float* tghw   = txw + (size_t)Bb*Cc*HWL;          // 1,769,472
  float* msite  = tghw + (size_t)Bb*Cc*SG;          // NBLK*1536 = 7,077,888
  float* part_row = msite + (size_t)NBLK*1536;      // NBLK*64
  float* pm1 = part_row + (size_t)NBLK*64;          // NBLK
  float* pm2 = pm1 + NBLK;                          // NBLK
  float* ps2 = pm2 + NBLK;                          // NBLK
  float* rowsum = ps2 + NBLK;                       // 128
  float* gmin = rowsum + 128;                       // 2
  float* s2v  = gmin + 2;                           // 2

  hipLaunchKernelGGL(conv_k, dim3(Bb*(SG/64)), dim3(256), 0, stream, g, W2, b2, tghw, SG);
  hipLaunchKernelGGL(conv_k, dim3(Bb*(HWL/64)), dim3(256), 0, stream, x, W1, b1, txw, HWL);
  hipLaunchKernelGGL(reduce_k, dim3(NBLK), dim3(256), 0, stream, txw, tghw, msite,
                     part_row, pm1, pm2, ps2);
  hipLaunchKernelGGL(reduce2_k, dim3(130), dim3(256), 0, stream, part_row, pm1, pm2, ps2,
                     rowsum, gmin, s2v);
  hipLaunchKernelGGL(final_k, dim3(NBLK), dim3(256), 0, stream, x, txw, msite,
                     gmin, rowsum, s2v, outp, outd);
}